// Round 8
// baseline (295.313 us; speedup 1.0000x reference)
//
#include <hip/hip_runtime.h>
#include <math.h>

#define P_NUM 8192
#define E_NUM 4194304
#define EPT 8

#define FOV_H 2.0943951f

typedef float f32x4 __attribute__((ext_vector_type(4)));
typedef int   i32x4 __attribute__((ext_vector_type(4)));

// ---------- prep A: fused 16-B exact record (r,theta,elev,pad) + elev residual ----------
__global__ __launch_bounds__(256) void fuse_prep(const float* __restrict__ patch_coords,
                                                 const float* __restrict__ elev,
                                                 const float* __restrict__ init_elev,
                                                 f32x4* __restrict__ fused,
                                                 float* __restrict__ out) {
    const int tid = blockIdx.x * blockDim.x + threadIdx.x;   // [0, E_NUM/4)
    const f32x4 a  = __builtin_nontemporal_load((const f32x4*)patch_coords + 2 * tid);
    const f32x4 b  = __builtin_nontemporal_load((const f32x4*)patch_coords + 2 * tid + 1);
    const f32x4 e  = __builtin_nontemporal_load((const f32x4*)elev + tid);
    const f32x4 ie = __builtin_nontemporal_load((const f32x4*)init_elev + tid);

    fused[4 * tid + 0] = (f32x4){a.x, a.y, e.x, 0.0f};
    fused[4 * tid + 1] = (f32x4){a.z, a.w, e.y, 0.0f};
    fused[4 * tid + 2] = (f32x4){b.x, b.y, e.z, 0.0f};
    fused[4 * tid + 3] = (f32x4){b.z, b.w, e.w, 0.0f};

    const f32x4 er = {e.x - ie.x, e.y - ie.y, e.z - ie.z, e.w - ie.w};
    __builtin_nontemporal_store(er, (f32x4*)(out + 2 * E_NUM + 7 * P_NUM) + tid);
}

// ---------- prep B: pad poses 7->8 floats + pose residual ----------
__global__ __launch_bounds__(256) void pose_prep(const float* __restrict__ poses,
                                                 const float* __restrict__ init_poses,
                                                 f32x4* __restrict__ pose8,
                                                 float* __restrict__ out) {
    const int tid = blockIdx.x * blockDim.x + threadIdx.x;   // [0, 14336)
    if (tid < P_NUM) {
        const float* s = poses + 7 * tid;
        pose8[2 * tid]     = (f32x4){s[0], s[1], s[2], s[3]};  // tx ty tz qx
        pose8[2 * tid + 1] = (f32x4){s[4], s[5], s[6], 0.0f};  // qy qz qw pad
    }
    if (tid < (7 * P_NUM) / 4) {
        const f32x4 a = ((const f32x4*)poses)[tid];
        const f32x4 b = ((const f32x4*)init_poses)[tid];
        const f32x4 r = {a.x - b.x, a.y - b.y, a.z - b.z, a.w - b.w};
        __builtin_nontemporal_store(r, (f32x4*)(out + 2 * E_NUM) + tid);
    }
}

__device__ __forceinline__ void quatrot(float ux, float uy, float uz, float uw,
                                        float vx, float vy, float vz,
                                        float& ox, float& oy, float& oz) {
    float tqx = 2.0f * (uy * vz - uz * vy);
    float tqy = 2.0f * (uz * vx - ux * vz);
    float tqz = 2.0f * (ux * vy - uy * vx);
    ox = vx + uw * tqx + (uy * tqz - uz * tqy);
    oy = vy + uw * tqy + (uz * tqx - ux * tqz);
    oz = vz + uw * tqz + (ux * tqy - uy * tqx);
}

__global__ __launch_bounds__(256) void ba_main(
    const f32x4* __restrict__ fused,   // E_NUM x (r,theta,elev,pad), ws
    const f32x4* __restrict__ pose8,   // ws
    const float* __restrict__ target,  // E_NUM*2
    const int*   __restrict__ src_idx,
    const int*   __restrict__ tgt_idx,
    const int*   __restrict__ patch_idx,
    float*       __restrict__ out)
{
    const int tid = blockIdx.x * blockDim.x + threadIdx.x;  // [0, E_NUM/EPT)

    const float R_RANGE = 30.0f - 0.5f;
    const float BINS    = 512.0f;
    const float BEAMS   = 512.0f;

    // streaming index loads (2x int4 per array for 8 edges)
    const i32x4 s4a = __builtin_nontemporal_load((const i32x4*)src_idx + 2 * tid);
    const i32x4 s4b = __builtin_nontemporal_load((const i32x4*)src_idx + 2 * tid + 1);
    const i32x4 t4a = __builtin_nontemporal_load((const i32x4*)tgt_idx + 2 * tid);
    const i32x4 t4b = __builtin_nontemporal_load((const i32x4*)tgt_idx + 2 * tid + 1);
    const i32x4 p4a = __builtin_nontemporal_load((const i32x4*)patch_idx + 2 * tid);
    const i32x4 p4b = __builtin_nontemporal_load((const i32x4*)patch_idx + 2 * tid + 1);
    const int si[EPT] = {s4a.x, s4a.y, s4a.z, s4a.w, s4b.x, s4b.y, s4b.z, s4b.w};
    const int ti[EPT] = {t4a.x, t4a.y, t4a.z, t4a.w, t4b.x, t4b.y, t4b.z, t4b.w};
    const int pi[EPT] = {p4a.x, p4a.y, p4a.z, p4a.w, p4b.x, p4b.y, p4b.z, p4b.w};

    // ---- issue all gathers up front (40 independent loads/thread) ----
    f32x4 rec[EPT];
    f32x4 slo[EPT], shi[EPT], tlo[EPT], thi[EPT];
#pragma unroll
    for (int e = 0; e < EPT; ++e) {
        rec[e] = fused[pi[e]];
        slo[e] = pose8[2 * si[e]];
        shi[e] = pose8[2 * si[e] + 1];
        tlo[e] = pose8[2 * ti[e]];
        thi[e] = pose8[2 * ti[e] + 1];
    }

    f32x4 tg[EPT / 2];
#pragma unroll
    for (int k = 0; k < EPT / 2; ++k)
        tg[k] = __builtin_nontemporal_load((const f32x4*)target + 4 * tid + k);

    float res[2 * EPT];
#pragma unroll
    for (int e = 0; e < EPT; ++e) {
        const float r  = rec[e].x;
        const float th = rec[e].y;
        const float ph = rec[e].z;
        const float cp = cosf(ph), sph = sinf(ph);
        const float ct = cosf(th), sth = sinf(th);
        float vx = r * cp * ct;
        float vy = r * cp * sth;
        float vz = r * sph;

        float gx, gy, gz;
        quatrot(slo[e].w, shi[e].x, shi[e].y, shi[e].z, vx, vy, vz, gx, gy, gz);
        gx += slo[e].x; gy += slo[e].y; gz += slo[e].z;

        float lx, ly, lz;
        quatrot(-tlo[e].w, -thi[e].x, -thi[e].y, thi[e].z,
                gx - tlo[e].x, gy - tlo[e].y, gz - tlo[e].z, lx, ly, lz);

        const float rr  = sqrtf(lx * lx + ly * ly + lz * lz);
        const float tth = atan2f(ly, lx);
        const float tgr  = (e & 1) ? tg[e >> 1].z : tg[e >> 1].x;
        const float tgth = (e & 1) ? tg[e >> 1].w : tg[e >> 1].y;
        res[2 * e]     = (rr  - tgr)  / R_RANGE * BINS;
        res[2 * e + 1] = (tth - tgth) / FOV_H * BEAMS;
    }

#pragma unroll
    for (int k = 0; k < EPT / 2; ++k) {
        const f32x4 o = {res[4 * k], res[4 * k + 1], res[4 * k + 2], res[4 * k + 3]};
        __builtin_nontemporal_store(o, (f32x4*)out + 4 * tid + k);
    }
}

extern "C" void kernel_launch(void* const* d_in, const int* in_sizes, int n_in,
                              void* d_out, int out_size, void* d_ws, size_t ws_size,
                              hipStream_t stream) {
    const float* poses        = (const float*)d_in[0];
    const float* init_poses   = (const float*)d_in[1];
    const float* patch_coords = (const float*)d_in[2];
    const float* elev         = (const float*)d_in[3];
    const float* init_elev    = (const float*)d_in[4];
    const float* target       = (const float*)d_in[5];
    const int*   src_idx      = (const int*)d_in[6];
    const int*   tgt_idx      = (const int*)d_in[7];
    const int*   patch_idx    = (const int*)d_in[8];
    float*       out          = (float*)d_out;

    f32x4* fused = (f32x4*)d_ws;                                   // 67.1 MB
    f32x4* pose8 = (f32x4*)((char*)d_ws + (size_t)E_NUM * 16);     // 256 KB

    pose_prep<<<(7 * P_NUM / 4) / 256, 256, 0, stream>>>(poses, init_poses, pose8, out);
    fuse_prep<<<(E_NUM / 4) / 256, 256, 0, stream>>>(patch_coords, elev, init_elev,
                                                     fused, out);

    const int block = 256;
    const int grid  = E_NUM / (block * EPT);    // 2048
    ba_main<<<grid, block, 0, stream>>>(fused, pose8, target, src_idx, tgt_idx,
                                        patch_idx, out);
}

// Round 9
// 268.748 us; speedup vs baseline: 1.0988x; 1.0988x over previous
//
#include <hip/hip_runtime.h>
#include <math.h>

#define P_NUM 8192
#define E_NUM 4194304
#define EPT 4

#define FOV_H 2.0943951f

typedef float f32x4 __attribute__((ext_vector_type(4)));
typedef int   i32x4 __attribute__((ext_vector_type(4)));

// ---------- prep: fused 16-B exact record (r,theta,elev,pad) + elev residual
// ----------       + pose8 padding + pose residual (merged, one dispatch)
__global__ __launch_bounds__(256) void fuse_prep(const float* __restrict__ patch_coords,
                                                 const float* __restrict__ elev,
                                                 const float* __restrict__ init_elev,
                                                 const float* __restrict__ poses,
                                                 const float* __restrict__ init_poses,
                                                 f32x4* __restrict__ fused,
                                                 f32x4* __restrict__ pose8,
                                                 float* __restrict__ out) {
    const int tid = blockIdx.x * blockDim.x + threadIdx.x;   // [0, E_NUM/4)
    const f32x4 a  = __builtin_nontemporal_load((const f32x4*)patch_coords + 2 * tid);
    const f32x4 b  = __builtin_nontemporal_load((const f32x4*)patch_coords + 2 * tid + 1);
    const f32x4 e  = __builtin_nontemporal_load((const f32x4*)elev + tid);
    const f32x4 ie = __builtin_nontemporal_load((const f32x4*)init_elev + tid);

    fused[4 * tid + 0] = (f32x4){a.x, a.y, e.x, 0.0f};
    fused[4 * tid + 1] = (f32x4){a.z, a.w, e.y, 0.0f};
    fused[4 * tid + 2] = (f32x4){b.x, b.y, e.z, 0.0f};
    fused[4 * tid + 3] = (f32x4){b.z, b.w, e.w, 0.0f};

    const f32x4 er = {e.x - ie.x, e.y - ie.y, e.z - ie.z, e.w - ie.w};
    __builtin_nontemporal_store(er, (f32x4*)(out + 2 * E_NUM + 7 * P_NUM) + tid);

    // pose work folded in: first P_NUM threads pad poses, first 14336 do residual
    if (tid < P_NUM) {
        const float* s = poses + 7 * tid;
        pose8[2 * tid]     = (f32x4){s[0], s[1], s[2], s[3]};  // tx ty tz qx
        pose8[2 * tid + 1] = (f32x4){s[4], s[5], s[6], 0.0f};  // qy qz qw pad
    }
    if (tid < (7 * P_NUM) / 4) {
        const f32x4 pa = ((const f32x4*)poses)[tid];
        const f32x4 pb = ((const f32x4*)init_poses)[tid];
        const f32x4 r = {pa.x - pb.x, pa.y - pb.y, pa.z - pb.z, pa.w - pb.w};
        __builtin_nontemporal_store(r, (f32x4*)(out + 2 * E_NUM) + tid);
    }
}

__device__ __forceinline__ void quatrot(float ux, float uy, float uz, float uw,
                                        float vx, float vy, float vz,
                                        float& ox, float& oy, float& oz) {
    float tqx = 2.0f * (uy * vz - uz * vy);
    float tqy = 2.0f * (uz * vx - ux * vz);
    float tqz = 2.0f * (ux * vy - uy * vx);
    ox = vx + uw * tqx + (uy * tqz - uz * tqy);
    oy = vy + uw * tqy + (uz * tqx - ux * tqz);
    oz = vz + uw * tqz + (ux * tqy - uy * tqx);
}

__global__ __launch_bounds__(256) void ba_main(
    const f32x4* __restrict__ fused,   // E_NUM x (r,theta,elev,pad), ws
    const f32x4* __restrict__ pose8,   // ws
    const float* __restrict__ target,  // E_NUM*2
    const int*   __restrict__ src_idx,
    const int*   __restrict__ tgt_idx,
    const int*   __restrict__ patch_idx,
    float*       __restrict__ out)
{
    const int tid = blockIdx.x * blockDim.x + threadIdx.x;  // [0, E_NUM/EPT)

    const float R_RANGE = 30.0f - 0.5f;
    const float BINS    = 512.0f;
    const float BEAMS   = 512.0f;

    // streaming index loads: non-temporal (don't evict the gather table)
    const i32x4 s4 = __builtin_nontemporal_load((const i32x4*)src_idx + tid);
    const i32x4 t4 = __builtin_nontemporal_load((const i32x4*)tgt_idx + tid);
    const i32x4 p4 = __builtin_nontemporal_load((const i32x4*)patch_idx + tid);
    const int si[EPT] = {s4.x, s4.y, s4.z, s4.w};
    const int ti[EPT] = {t4.x, t4.y, t4.z, t4.w};
    const int pi[EPT] = {p4.x, p4.y, p4.z, p4.w};

    // ---- issue all gathers up front (cached: table + poses) ----
    f32x4 rec[EPT];
    f32x4 slo[EPT], shi[EPT], tlo[EPT], thi[EPT];
#pragma unroll
    for (int e = 0; e < EPT; ++e) {
        rec[e] = fused[pi[e]];
        slo[e] = pose8[2 * si[e]];
        shi[e] = pose8[2 * si[e] + 1];
        tlo[e] = pose8[2 * ti[e]];
        thi[e] = pose8[2 * ti[e] + 1];
    }

    const f32x4 tg01 = __builtin_nontemporal_load((const f32x4*)target + 2 * tid);
    const f32x4 tg23 = __builtin_nontemporal_load((const f32x4*)target + 2 * tid + 1);
    const float tgr[EPT]  = {tg01.x, tg01.z, tg23.x, tg23.z};
    const float tgth[EPT] = {tg01.y, tg01.w, tg23.y, tg23.w};

    float res[2 * EPT];
#pragma unroll
    for (int e = 0; e < EPT; ++e) {
        const float r  = rec[e].x;
        const float th = rec[e].y;
        const float ph = rec[e].z;
        const float cp = cosf(ph), sph = sinf(ph);
        const float ct = cosf(th), sth = sinf(th);
        float vx = r * cp * ct;
        float vy = r * cp * sth;
        float vz = r * sph;

        float gx, gy, gz;
        quatrot(slo[e].w, shi[e].x, shi[e].y, shi[e].z, vx, vy, vz, gx, gy, gz);
        gx += slo[e].x; gy += slo[e].y; gz += slo[e].z;

        float lx, ly, lz;
        quatrot(-tlo[e].w, -thi[e].x, -thi[e].y, thi[e].z,
                gx - tlo[e].x, gy - tlo[e].y, gz - tlo[e].z, lx, ly, lz);

        const float rr  = sqrtf(lx * lx + ly * ly + lz * lz);
        const float tth = atan2f(ly, lx);
        res[2 * e]     = (rr  - tgr[e])  / R_RANGE * BINS;
        res[2 * e + 1] = (tth - tgth[e]) / FOV_H * BEAMS;
    }

    const f32x4 o0 = {res[0], res[1], res[2], res[3]};
    const f32x4 o1 = {res[4], res[5], res[6], res[7]};
    __builtin_nontemporal_store(o0, (f32x4*)out + 2 * tid);
    __builtin_nontemporal_store(o1, (f32x4*)out + 2 * tid + 1);
}

extern "C" void kernel_launch(void* const* d_in, const int* in_sizes, int n_in,
                              void* d_out, int out_size, void* d_ws, size_t ws_size,
                              hipStream_t stream) {
    const float* poses        = (const float*)d_in[0];
    const float* init_poses   = (const float*)d_in[1];
    const float* patch_coords = (const float*)d_in[2];
    const float* elev         = (const float*)d_in[3];
    const float* init_elev    = (const float*)d_in[4];
    const float* target       = (const float*)d_in[5];
    const int*   src_idx      = (const int*)d_in[6];
    const int*   tgt_idx      = (const int*)d_in[7];
    const int*   patch_idx    = (const int*)d_in[8];
    float*       out          = (float*)d_out;

    f32x4* fused = (f32x4*)d_ws;                                   // 67.1 MB
    f32x4* pose8 = (f32x4*)((char*)d_ws + (size_t)E_NUM * 16);     // 256 KB

    fuse_prep<<<(E_NUM / 4) / 256, 256, 0, stream>>>(patch_coords, elev, init_elev,
                                                     poses, init_poses,
                                                     fused, pose8, out);

    const int block = 256;
    const int grid  = E_NUM / (block * EPT);    // 4096
    ba_main<<<grid, block, 0, stream>>>(fused, pose8, target, src_idx, tgt_idx,
                                        patch_idx, out);
}